// Round 1
// baseline (3206.290 us; speedup 1.0000x reference)
//
#include <hip/hip_runtime.h>
#include <math.h>

#define B_ 16
#define N_ 256
#define L_ 32
#define NN_ (N_*N_)          // 65536
#define NNL_ (NN_*L_)        // 2097152 elements per batch
#define ANN_ (B_*NN_)        // 1048576
#define POTS_OFF 4096        // float offset where big arrays start
#define NEGINF -1.0e30f

// ws float layout (float* W = (float*)d_ws):
//   [0 .. 2048)  : 1024 doubles — stats partials [B][32][2]
//   [2048..2080) : stats (mean, invstd) per batch
//   W + POTS_OFF + k*ANN_ for k = 0..11:
//     0: pot1 (start,width)   1: sbar    2: pot2    3: pot3
//     4: cs0  5: ce0  6: hs0  7: he0   (z_full pass + expectation semiring)
//     8: cs1  9: ce1                   (z_smooth pass)
//    10: cs2 11: ce2                   (z_partial pass)
//   W + POTS_OFF + 12*ANN_: zres[64] = {z_full[16], z_smooth[16], z_partial[16], h_root[16]}
// total ~50.4 MB

// ---------------- wave helpers ----------------
__device__ __forceinline__ float max16(float v) {
#pragma unroll
    for (int k = 8; k >= 1; k >>= 1) v = fmaxf(v, __shfl_xor(v, k));
    return v;
}
__device__ __forceinline__ float sum16(float v) {
#pragma unroll
    for (int k = 8; k >= 1; k >>= 1) v += __shfl_xor(v, k);
    return v;
}
__device__ __forceinline__ float max32(float v) {
#pragma unroll
    for (int k = 16; k >= 1; k >>= 1) v = fmaxf(v, __shfl_xor(v, k));
    return v;
}
__device__ __forceinline__ float sum32(float v) {
#pragma unroll
    for (int k = 16; k >= 1; k >>= 1) v += __shfl_xor(v, k);
    return v;
}

// ---------------- kernel 1a: per-batch sum/sumsq partials ----------------
__global__ void stats_partial(const float* __restrict__ lp, double* __restrict__ part) {
    int blk = blockIdx.x;            // 0..511 = B*32
    int b = blk >> 5, seg = blk & 31;
    const float4* p4 = (const float4*)(lp + (size_t)b * NNL_ + (size_t)seg * (NNL_ / 32));
    double s = 0.0, ss = 0.0;
    for (int idx = threadIdx.x; idx < (NNL_ / 32 / 4); idx += 256) {
        float4 v = p4[idx];
        s  += (double)v.x + (double)v.y + (double)v.z + (double)v.w;
        ss += (double)v.x * v.x + (double)v.y * v.y + (double)v.z * v.z + (double)v.w * v.w;
    }
    __shared__ double sh0[256], sh1[256];
    sh0[threadIdx.x] = s; sh1[threadIdx.x] = ss;
    __syncthreads();
    for (int off = 128; off > 0; off >>= 1) {
        if (threadIdx.x < off) {
            sh0[threadIdx.x] += sh0[threadIdx.x + off];
            sh1[threadIdx.x] += sh1[threadIdx.x + off];
        }
        __syncthreads();
    }
    if (threadIdx.x == 0) { part[blk * 2] = sh0[0]; part[blk * 2 + 1] = sh1[0]; }
}

// ---------------- kernel 1b: finalize mean/invstd ----------------
__global__ void stats_final(const double* __restrict__ part, float* __restrict__ stats) {
    int b = threadIdx.x;
    if (b >= B_) return;
    double s = 0.0, ss = 0.0;
    for (int k = 0; k < 32; ++k) { s += part[(b * 32 + k) * 2]; ss += part[(b * 32 + k) * 2 + 1]; }
    double n = (double)NNL_;
    double mean = s / n;
    double var = (ss - s * s / n) / (n - 1.0);
    stats[b * 2]     = (float)mean;
    stats[b * 2 + 1] = (float)(1.0 / sqrt(var));
}

// ---------------- kernel 2: label-logsumexp -> span potentials ----------------
// One 32-lane group per upper-triangle cell (b, i, w) with j = i+w < N.
__global__ void pots_kernel(const float* __restrict__ lp, const float* __restrict__ evm,
                            const float* __restrict__ stats, float* __restrict__ W) {
    int t = threadIdx.x;
    int c = blockIdx.x * 8 + (t >> 5);
    int lane = t & 31;
    int b = c >> 16;
    int rem = c & (NN_ - 1);
    int i = rem >> 8;
    int w = rem & (N_ - 1);
    if (i + w >= N_) return;                 // lower wrap cells never used
    int j = i + w;
    int base = ((b * NN_ + i * N_ + j) << 5) + lane;
    float mean = stats[b * 2], invstd = stats[b * 2 + 1];
    float x  = (lp[base] - mean) * invstd;
    float em = evm[base];
    // pass1: lse + sbar
    float m1 = max32(x);
    float e1 = expf(x - m1);
    float s1 = sum32(e1);
    float n1 = sum32(e1 * x);
    // pass2: smooth mask
    float y  = x + logf(em + (1.0f - em) * 0.1f + 1e-10f);
    float m2 = max32(y);
    float s2 = sum32(expf(y - m2));
    // pass3: hard mask
    float z  = x - 1e6f * (1.0f - em);
    float m3 = max32(z);
    float s3 = sum32(expf(z - m3));
    if (lane == 0) {
        int o = b * NN_ + i * N_ + w;        // (start, width) layout
        W[POTS_OFF + 0 * ANN_ + o] = m1 + logf(s1);
        W[POTS_OFF + 1 * ANN_ + o] = n1 / s1;
        W[POTS_OFF + 2 * ANN_ + o] = m2 + logf(s2);
        W[POTS_OFF + 3 * ANN_ + o] = m3 + logf(s3);
    }
}

// ---------------- kernel 3: CKY inside (optionally with expectation semiring) ----
// EXP=true : grid = B blocks, pass 0 (z_full + h for entropy)
// EXP=false: grid = 2*B blocks, p = bx>>4 in {0,1} -> passes 2,3
template <bool EXP>
__global__ __launch_bounds__(1024)
void cky_kernel(float* __restrict__ W, const int* __restrict__ lengths) {
    int bx = blockIdx.x;
    int b, p;
    const float* pot; const float* sbr = nullptr;
    float* cs; float* ce; float* hs = nullptr; float* he = nullptr;
    float* zres = W + POTS_OFF + 12 * ANN_;
    if (EXP) {
        b = bx; p = 0;
        pot = W + POTS_OFF + 0 * ANN_ + b * NN_;
        sbr = W + POTS_OFF + 1 * ANN_ + b * NN_;
        cs  = W + POTS_OFF + 4 * ANN_ + b * NN_;
        ce  = W + POTS_OFF + 5 * ANN_ + b * NN_;
        hs  = W + POTS_OFF + 6 * ANN_ + b * NN_;
        he  = W + POTS_OFF + 7 * ANN_ + b * NN_;
    } else {
        p = bx >> 4; b = bx & 15;
        pot = W + POTS_OFF + (p ? 3 : 2) * ANN_ + b * NN_;
        cs  = W + POTS_OFF + (p ? 10 : 8) * ANN_ + b * NN_;
        ce  = W + POTS_OFF + (p ? 11 : 9) * ANN_ + b * NN_;
    }
    int len = lengths[b];
    if (len < 1) len = 1;
    if (len > N_) len = N_;
    int tid = threadIdx.x;

    // width-0 init
    for (int i = tid; i < N_; i += 1024) {
        float v = pot[i * N_];
        cs[i * N_] = v; ce[i * N_] = v;
        if (EXP) { float s0 = sbr[i * N_]; hs[i * N_] = s0; he[i * N_] = s0; }
    }
    __syncthreads();

    int group = tid >> 4, lane = tid & 15;   // 64 groups of 16 lanes
    for (int w = 1; w < len; ++w) {
        int cells = len - w;                 // starts i = 0..cells-1
        for (int i = group; i < cells; i += 64) {
            int j = i + w;
            const float* csr = cs + i * N_;
            const float* cer = ce + j * N_;
            // pass A: max over splits
            float m = NEGINF;
            for (int u = lane; u < w; u += 16)
                m = fmaxf(m, csr[u] + cer[w - 1 - u]);
            m = max16(m);
            // pass B: sum exp (and expectation numerator)
            float s = 0.f, nacc = 0.f;
            if (EXP) {
                const float* hsr = hs + i * N_;
                const float* her = he + j * N_;
                for (int u = lane; u < w; u += 16) {
                    float e = csr[u] + cer[w - 1 - u];
                    float t = expf(e - m);
                    s += t;
                    nacc += t * (hsr[u] + her[w - 1 - u]);
                }
            } else {
                for (int u = lane; u < w; u += 16) {
                    float e = csr[u] + cer[w - 1 - u];
                    s += expf(e - m);
                }
            }
            s = sum16(s);
            if (EXP) nacc = sum16(nacc);
            float v = pot[i * N_ + w] + m + logf(s);
            if (lane == 0) {
                cs[i * N_ + w] = v;
                ce[j * N_ + w] = v;
                if (EXP) {
                    float hval = sbr[i * N_ + w] + nacc / s;
                    hs[i * N_ + w] = hval;
                    he[j * N_ + w] = hval;
                }
            }
        }
        __syncthreads();
    }

    if (tid == 0) {
        float root = cs[len - 1];            // cs[0][len-1]
        if (EXP) { zres[b] = root; zres[48 + b] = hs[len - 1]; }
        else     { zres[(p ? 32 : 16) + b] = root; }
    }
}

// ---------------- kernel 4: combine outputs ----------------
__global__ void combine_kernel(const float* __restrict__ W, float* __restrict__ out) {
    int b = threadIdx.x;
    if (b >= B_) return;
    const float* zres = W + POTS_OFF + 12 * ANN_;
    float zf = zres[b], zs = zres[16 + b], zp = zres[32 + b], hr = zres[48 + b];
    out[b]          = zp - zf;   // log_prob
    out[16 + b]     = zs - zf;   // log_prob_smooth
    out[32 + b]     = zf - hr;   // entropy = z_full - E[sum sbar]
}

extern "C" void kernel_launch(void* const* d_in, const int* in_sizes, int n_in,
                              void* d_out, int out_size, void* d_ws, size_t ws_size,
                              hipStream_t stream) {
    const float* lp      = (const float*)d_in[0];
    // d_in[1] (mask) is unused by the reference
    const int*   lengths = (const int*)d_in[2];
    const float* evm     = (const float*)d_in[3];
    float*  W    = (float*)d_ws;
    double* part = (double*)d_ws;
    float*  stats = W + 2048;
    float*  out  = (float*)d_out;

    stats_partial<<<B_ * 32, 256, 0, stream>>>(lp, part);
    stats_final<<<1, 64, 0, stream>>>(part, stats);
    pots_kernel<<<(B_ * NN_) / 8, 256, 0, stream>>>(lp, evm, stats, W);
    cky_kernel<true><<<B_, 1024, 0, stream>>>(W, lengths);
    cky_kernel<false><<<2 * B_, 1024, 0, stream>>>(W, lengths);
    combine_kernel<<<1, 64, 0, stream>>>(W, out);
}

// Round 2
// 1741.656 us; speedup vs baseline: 1.8409x; 1.8409x over previous
//
#include <hip/hip_runtime.h>
#include <math.h>

#define B_ 16
#define N_ 256
#define L_ 32
#define NN_ (N_*N_)          // 65536
#define NNL_ (NN_*L_)        // 2097152 elements per batch
#define ANN_ (B_*NN_)        // 1048576
#define POTS_OFF 4096        // float offset where big arrays start
#define NEGINF -1.0e30f

// ws float layout (float* W = (float*)d_ws):
//   [0 .. 2048)  : 1024 doubles — stats partials [B][32][2]
//   [2048..2080) : stats (mean, invstd) per batch
//   W + POTS_OFF + k*ANN_ for k = 0..11:
//     0: pot1 (start,width)   1: sbar    2: pot2    3: pot3
//     4: cs0  5: ce0  6: hs0  7: he0   (z_full pass + expectation semiring)
//     8: cs1  9: ce1                   (z_smooth pass)
//    10: cs2 11: ce2                   (z_partial pass)
//   W + POTS_OFF + 12*ANN_: zres[64] = {z_full[16], z_smooth[16], z_partial[16], h_root[16]}

// ---------------- wave helpers ----------------
__device__ __forceinline__ float max16(float v) {
#pragma unroll
    for (int k = 8; k >= 1; k >>= 1) v = fmaxf(v, __shfl_xor(v, k));
    return v;
}
__device__ __forceinline__ float sum16(float v) {
#pragma unroll
    for (int k = 8; k >= 1; k >>= 1) v += __shfl_xor(v, k);
    return v;
}
__device__ __forceinline__ float max32(float v) {
#pragma unroll
    for (int k = 16; k >= 1; k >>= 1) v = fmaxf(v, __shfl_xor(v, k));
    return v;
}
__device__ __forceinline__ float sum32(float v) {
#pragma unroll
    for (int k = 16; k >= 1; k >>= 1) v += __shfl_xor(v, k);
    return v;
}

// ---------------- kernel 1a: per-batch sum/sumsq partials ----------------
__global__ void stats_partial(const float* __restrict__ lp, double* __restrict__ part) {
    int blk = blockIdx.x;            // 0..511 = B*32
    int b = blk >> 5, seg = blk & 31;
    const float4* p4 = (const float4*)(lp + (size_t)b * NNL_ + (size_t)seg * (NNL_ / 32));
    double s = 0.0, ss = 0.0;
    for (int idx = threadIdx.x; idx < (NNL_ / 32 / 4); idx += 256) {
        float4 v = p4[idx];
        s  += (double)v.x + (double)v.y + (double)v.z + (double)v.w;
        ss += (double)v.x * v.x + (double)v.y * v.y + (double)v.z * v.z + (double)v.w * v.w;
    }
    __shared__ double sh0[256], sh1[256];
    sh0[threadIdx.x] = s; sh1[threadIdx.x] = ss;
    __syncthreads();
    for (int off = 128; off > 0; off >>= 1) {
        if (threadIdx.x < off) {
            sh0[threadIdx.x] += sh0[threadIdx.x + off];
            sh1[threadIdx.x] += sh1[threadIdx.x + off];
        }
        __syncthreads();
    }
    if (threadIdx.x == 0) { part[blk * 2] = sh0[0]; part[blk * 2 + 1] = sh1[0]; }
}

// ---------------- kernel 1b: finalize mean/invstd ----------------
__global__ void stats_final(const double* __restrict__ part, float* __restrict__ stats) {
    int b = threadIdx.x;
    if (b >= B_) return;
    double s = 0.0, ss = 0.0;
    for (int k = 0; k < 32; ++k) { s += part[(b * 32 + k) * 2]; ss += part[(b * 32 + k) * 2 + 1]; }
    double n = (double)NNL_;
    double mean = s / n;
    double var = (ss - s * s / n) / (n - 1.0);
    stats[b * 2]     = (float)mean;
    stats[b * 2 + 1] = (float)(1.0 / sqrt(var));
}

// ---------------- kernel 2: label-logsumexp -> span potentials ----------------
__global__ void pots_kernel(const float* __restrict__ lp, const float* __restrict__ evm,
                            const float* __restrict__ stats, float* __restrict__ W) {
    int t = threadIdx.x;
    int c = blockIdx.x * 8 + (t >> 5);
    int lane = t & 31;
    int b = c >> 16;
    int rem = c & (NN_ - 1);
    int i = rem >> 8;
    int w = rem & (N_ - 1);
    if (i + w >= N_) return;                 // lower wrap cells never used
    int j = i + w;
    int base = ((b * NN_ + i * N_ + j) << 5) + lane;
    float mean = stats[b * 2], invstd = stats[b * 2 + 1];
    float x  = (lp[base] - mean) * invstd;
    float em = evm[base];
    // pass1: lse + sbar
    float m1 = max32(x);
    float e1 = __expf(x - m1);
    float s1 = sum32(e1);
    float n1 = sum32(e1 * x);
    // pass2: smooth mask
    float y  = x + __logf(em + (1.0f - em) * 0.1f + 1e-10f);
    float m2 = max32(y);
    float s2 = sum32(__expf(y - m2));
    // pass3: hard mask
    float z  = x - 1e6f * (1.0f - em);
    float m3 = max32(z);
    float s3 = sum32(__expf(z - m3));
    if (lane == 0) {
        int o = b * NN_ + i * N_ + w;        // (start, width) layout
        W[POTS_OFF + 0 * ANN_ + o] = m1 + __logf(s1);
        W[POTS_OFF + 1 * ANN_ + o] = n1 / s1;
        W[POTS_OFF + 2 * ANN_ + o] = m2 + __logf(s2);
        W[POTS_OFF + 3 * ANN_ + o] = m3 + __logf(s3);
    }
}

// ---------------- kernel 3: all three CKY inside passes in one launch --------
// grid = 3*B blocks: p = bx>>4 in {0(z_full+entropy h), 1(smooth), 2(partial)}
__global__ __launch_bounds__(1024)
void cky_all(float* __restrict__ W, const int* __restrict__ lengths) {
    int bx = blockIdx.x;
    int p = bx >> 4, b = bx & 15;
    const bool expmode = (p == 0);
    const float* pot; const float* sbr;
    float *cs, *ce, *hs, *he;
    float* zres = W + POTS_OFF + 12 * ANN_;
    if (p == 0) {
        pot = W + POTS_OFF + 0 * ANN_ + b * NN_;
        sbr = W + POTS_OFF + 1 * ANN_ + b * NN_;
        cs  = W + POTS_OFF + 4 * ANN_ + b * NN_;
        ce  = W + POTS_OFF + 5 * ANN_ + b * NN_;
        hs  = W + POTS_OFF + 6 * ANN_ + b * NN_;
        he  = W + POTS_OFF + 7 * ANN_ + b * NN_;
    } else if (p == 1) {
        pot = W + POTS_OFF + 2 * ANN_ + b * NN_; sbr = pot;
        cs  = W + POTS_OFF + 8 * ANN_ + b * NN_;
        ce  = W + POTS_OFF + 9 * ANN_ + b * NN_;
        hs = cs; he = ce;
    } else {
        pot = W + POTS_OFF + 3 * ANN_ + b * NN_; sbr = pot;
        cs  = W + POTS_OFF + 10 * ANN_ + b * NN_;
        ce  = W + POTS_OFF + 11 * ANN_ + b * NN_;
        hs = cs; he = ce;
    }
    int len = lengths[b];
    if (len < 1) len = 1;
    if (len > N_) len = N_;
    int tid = threadIdx.x;

    // width-0 init
    for (int i = tid; i < N_; i += 1024) {
        float v = pot[i * N_];
        cs[i * N_] = v; ce[i * N_] = v;
        if (expmode) { float s0 = sbr[i * N_]; hs[i * N_] = s0; he[i * N_] = s0; }
    }
    __syncthreads();

    int group = tid >> 4, lane = tid & 15;   // 64 groups of 16 lanes
    for (int w = 1; w < len; ++w) {
        int cells = len - w;
        int kmax = (w + 15) >> 4;            // uniform across block
        for (int i = group; i < cells; i += 64) {
            int j = i + w;
            const float* csr = cs + i * N_;
            const float* cer = ce + j * N_;
            const float* hsr = hs + i * N_;
            const float* her = he + j * N_;
            // single load pass: cache split values in registers, track max
            float e[16], hv[16];
            float m = NEGINF;
#pragma unroll
            for (int k = 0; k < 16; ++k) {
                e[k] = NEGINF; hv[k] = 0.f;
                if (k < kmax) {
                    int u = lane + (k << 4);
                    if (u < w) {
                        float ev = csr[u] + cer[w - 1 - u];
                        e[k] = ev;
                        if (expmode) hv[k] = hsr[u] + her[w - 1 - u];
                        m = fmaxf(m, ev);
                    }
                }
            }
            m = max16(m);
            // exp-sum from registers (no reload)
            float s = 0.f, nacc = 0.f;
#pragma unroll
            for (int k = 0; k < 16; ++k) {
                if (k < kmax) {
                    float t = __expf(e[k] - m);   // invalid slots: exp(-1e30-m) = 0
                    s += t;
                    if (expmode) nacc += t * hv[k];
                }
            }
            s = sum16(s);
            if (expmode) nacc = sum16(nacc);
            float v = pot[i * N_ + w] + m + __logf(s);
            if (lane == 0) {
                cs[i * N_ + w] = v;
                ce[j * N_ + w] = v;
                if (expmode) {
                    float hval = sbr[i * N_ + w] + nacc / s;
                    hs[i * N_ + w] = hval;
                    he[j * N_ + w] = hval;
                }
            }
        }
        __syncthreads();
    }

    if (tid == 0) {
        float root = cs[len - 1];            // cs[0][len-1]
        if (p == 0) { zres[b] = root; zres[48 + b] = hs[len - 1]; }
        else        { zres[p * 16 + b] = root; }
    }
}

// ---------------- kernel 4: combine outputs ----------------
__global__ void combine_kernel(const float* __restrict__ W, float* __restrict__ out) {
    int b = threadIdx.x;
    if (b >= B_) return;
    const float* zres = W + POTS_OFF + 12 * ANN_;
    float zf = zres[b], zs = zres[16 + b], zp = zres[32 + b], hr = zres[48 + b];
    out[b]          = zp - zf;   // log_prob
    out[16 + b]     = zs - zf;   // log_prob_smooth
    out[32 + b]     = zf - hr;   // entropy = z_full - E[sum sbar]
}

extern "C" void kernel_launch(void* const* d_in, const int* in_sizes, int n_in,
                              void* d_out, int out_size, void* d_ws, size_t ws_size,
                              hipStream_t stream) {
    const float* lp      = (const float*)d_in[0];
    // d_in[1] (mask) is unused by the reference
    const int*   lengths = (const int*)d_in[2];
    const float* evm     = (const float*)d_in[3];
    float*  W    = (float*)d_ws;
    double* part = (double*)d_ws;
    float*  stats = W + 2048;
    float*  out  = (float*)d_out;

    stats_partial<<<B_ * 32, 256, 0, stream>>>(lp, part);
    stats_final<<<1, 64, 0, stream>>>(part, stats);
    pots_kernel<<<(B_ * NN_) / 8, 256, 0, stream>>>(lp, evm, stats, W);
    cky_all<<<3 * B_, 1024, 0, stream>>>(W, lengths);
    combine_kernel<<<1, 64, 0, stream>>>(W, out);
}